// Round 1
// baseline (863.869 us; speedup 1.0000x reference)
//
#include <hip/hip_runtime.h>

#define S_LEN 2048
#define D_DIM 64

typedef __attribute__((ext_vector_type(8))) _Float16 half8;
typedef __attribute__((ext_vector_type(4))) _Float16 half4;
typedef __attribute__((ext_vector_type(2))) _Float16 half2v;
typedef __attribute__((ext_vector_type(4))) float    floatx4;
typedef __attribute__((ext_vector_type(4))) int      intx4;
typedef __attribute__((ext_vector_type(4))) unsigned uint4v;

static constexpr size_t NELEM = (size_t)2 * 16 * 2048 * 64;  // 4,194,304 per tensor
// fold 1/sqrt(d)=0.125 and log2(e) into Q so softmax uses native exp2
static constexpr float QSCALE = 0.125f * 1.44269504088896340736f;

// ---------------------------------------------------------------------------
// Kernel 1: fp32 -> fp16. Qh = q * (0.125*log2e), Kh = k, Vt = V^T per (b,h):
// [bh][d=64][s=2048] so PV B-frags are contiguous. 1024 blocks x 256 thr.
// ---------------------------------------------------------------------------
__global__ __launch_bounds__(256) void cvt_kernel(const float* __restrict__ q,
                                                  const float* __restrict__ k,
                                                  const float* __restrict__ v,
                                                  _Float16* __restrict__ Qh,
                                                  _Float16* __restrict__ Kh,
                                                  _Float16* __restrict__ Vt) {
  __shared__ float lds[64][65];  // +1 pad: conflict-free column reads
  const int t  = threadIdx.x;
  const int bh = blockIdx.x >> 5;
  const int st = blockIdx.x & 31;
  const size_t base = (size_t)bh * (S_LEN * D_DIM) + (size_t)st * (64 * D_DIM);

#pragma unroll
  for (int i = 0; i < 4; ++i) {
    size_t e = base + (size_t)(t + 256 * i) * 4;
    floatx4 qv = *(const floatx4*)(q + e);
    floatx4 kv = *(const floatx4*)(k + e);
    half4 qh, kh;
#pragma unroll
    for (int j = 0; j < 4; ++j) {
      qh[j] = (_Float16)(qv[j] * QSCALE);
      kh[j] = (_Float16)kv[j];
    }
    *(half4*)(Qh + e) = qh;
    *(half4*)(Kh + e) = kh;
  }

  {
    const int row = t >> 2;
    const int c4  = t & 3;
#pragma unroll
    for (int i = 0; i < 4; ++i) {
      int col = (c4 + 4 * i) * 4;
      floatx4 vv = *(const floatx4*)(v + base + (size_t)row * D_DIM + col);
      lds[row][col + 0] = vv[0];
      lds[row][col + 1] = vv[1];
      lds[row][col + 2] = vv[2];
      lds[row][col + 3] = vv[3];
    }
  }
  __syncthreads();
  {
    const int d = t >> 2;
    const int j = t & 3;
    half8 t0, t1;
#pragma unroll
    for (int u = 0; u < 8; ++u) t0[u] = (_Float16)lds[j * 16 + u][d];
#pragma unroll
    for (int u = 0; u < 8; ++u) t1[u] = (_Float16)lds[j * 16 + 8 + u][d];
    size_t ob = (size_t)bh * (D_DIM * S_LEN) + (size_t)d * S_LEN + st * 64 + j * 16;
    *(half8*)(Vt + ob)     = t0;
    *(half8*)(Vt + ob + 8) = t1;
  }
}

// ---------------------------------------------------------------------------
// Kernel 2: fused attention, ZERO LDS / ZERO barriers. One WG = (b,h) x 64
// q-rows, 4 independent waves x 16 q-rows. Swapped QK^T: s = mfma(K, Q) so
// D-layout puts q = lane&15 (col) and k = quad*4+r (row) -> softmax row is
// lane-local. Per kt (64 k):
//   phase1: esum += sum_k mask*exp2(s);  reduce via shfl_xor(16|32).
//   phase2: w = mask*exp2(s)*linv, float4 nontemporal store (the 536MB
//           output), pack w->fp16 pairs, in-register C->A transpose via
//           v_permlane32_swap + v_permlane16_swap (replaces the old ldsW
//           round trip + 2 barriers), PV MFMA on V^T frags from global.
// K/V fragment loads come straight from global: per-kt tiles are 8KB
// (L1-resident), per-bh K/V 512KB (L2-resident w/ XCD-contiguous swizzle).
// MFMA 16x16x32 f16 layouts (learn_hip-verified family):
//   A: m=lane&15, k=quad*8+j    B: n=lane&15, k=quad*8+j
//   C/D: col=lane&15, row=quad*4+reg
// ---------------------------------------------------------------------------
__global__ __launch_bounds__(256, 4) void attn_kernel(
    const _Float16* __restrict__ Qh, const _Float16* __restrict__ Kh,
    const _Float16* __restrict__ Vt, const int* __restrict__ mask,
    float* __restrict__ out, float* __restrict__ wout) {
  const int t    = threadIdx.x;
  // XCD-contiguous swizzle: grid 1024 % 8 == 0, each XCD gets 4 full bh.
  const int swz  = ((blockIdx.x & 7) << 7) | (blockIdx.x >> 3);
  const int bh   = swz >> 5;
  const int qt   = swz & 31;
  const int b    = bh >> 4;  // H = 16
  const int q0   = qt * 64;
  const int wv   = t >> 6;
  const int lane = t & 63;
  const int l15  = lane & 15;
  const int quad = lane >> 4;

  const int* __restrict__ mrow = mask + (size_t)b * S_LEN;
  const _Float16* __restrict__ Kbh = Kh + (size_t)bh * (S_LEN * D_DIM);
  const _Float16* __restrict__ Vbh = Vt + (size_t)bh * (D_DIM * S_LEN);

  // Q fragments (B-operand now): n = lane&15 = q-row, k-dim = quad*8+j
  const _Float16* Qp =
      Qh + ((size_t)bh * S_LEN + q0 + wv * 16 + l15) * D_DIM + quad * 8;
  const half8 qf0 = *(const half8*)(Qp);
  const half8 qf1 = *(const half8*)(Qp + 32);

  // ---- phase 1: row sums of exp2(scores) ----
  float esum = 0.f;
  for (int kt = 0; kt < 32; ++kt) {
    const _Float16* kb = Kbh + (size_t)kt * (64 * D_DIM) + quad * 8;
    const int* mb = mrow + kt * 64 + quad * 4;
#pragma unroll
    for (int n = 0; n < 4; ++n) {
      const _Float16* kp = kb + (size_t)(n * 16 + l15) * D_DIM;
      half8 a0 = *(const half8*)kp;         // d = quad*8..+7
      half8 a1 = *(const half8*)(kp + 32);  // d = 32+quad*8..+7
      floatx4 s = {0.f, 0.f, 0.f, 0.f};
      s = __builtin_amdgcn_mfma_f32_16x16x32_f16(a0, qf0, s, 0, 0, 0);
      s = __builtin_amdgcn_mfma_f32_16x16x32_f16(a1, qf1, s, 0, 0, 0);
      intx4 mi = *(const intx4*)(mb + n * 16);  // k = kt*64+n*16+quad*4+r
#pragma unroll
      for (int r = 0; r < 4; ++r)
        esum += mi[r] ? __builtin_exp2f(s[r]) : 0.f;
    }
  }
  esum += __shfl_xor(esum, 16);
  esum += __shfl_xor(esum, 32);
  const float linv = 1.0f / esum;  // every lane: full row sum for q = l15

  // ---- phase 2: weights out + O accumulate ----
  floatx4 oacc[4];
#pragma unroll
  for (int nd = 0; nd < 4; ++nd) oacc[nd] = (floatx4){0.f, 0.f, 0.f, 0.f};

  float* __restrict__ wrow =
      wout + ((size_t)bh * S_LEN + q0 + wv * 16 + l15) * S_LEN;

  for (int kt = 0; kt < 32; ++kt) {
    const _Float16* kb = Kbh + (size_t)kt * (64 * D_DIM) + quad * 8;
    const int* mb = mrow + kt * 64 + quad * 4;
    unsigned pw[4][2];  // pw[n][h]: fp16 pair for k = 16n + 4*quad + 2h,+1
#pragma unroll
    for (int n = 0; n < 4; ++n) {
      const _Float16* kp = kb + (size_t)(n * 16 + l15) * D_DIM;
      half8 a0 = *(const half8*)kp;
      half8 a1 = *(const half8*)(kp + 32);
      floatx4 s = {0.f, 0.f, 0.f, 0.f};
      s = __builtin_amdgcn_mfma_f32_16x16x32_f16(a0, qf0, s, 0, 0, 0);
      s = __builtin_amdgcn_mfma_f32_16x16x32_f16(a1, qf1, s, 0, 0, 0);
      intx4 mi = *(const intx4*)(mb + n * 16);
      floatx4 w;
#pragma unroll
      for (int r = 0; r < 4; ++r)
        w[r] = mi[r] ? __builtin_exp2f(s[r]) * linv : 0.f;
      // lane holds 4 consecutive k -> coalesced float4, pure streaming
      __builtin_nontemporal_store(
          w, (floatx4*)(wrow + kt * 64 + n * 16 + quad * 4));
      half2v h0 = {(_Float16)w[0], (_Float16)w[1]};  // RTN, matches prior ver
      half2v h1 = {(_Float16)w[2], (_Float16)w[3]};
      pw[n][0] = __builtin_bit_cast(unsigned, h0);
      pw[n][1] = __builtin_bit_cast(unsigned, h1);
    }

    // In-register C->A transpose. Pair (P[2c][h], P[2c+1][h]) ->
    // permlane32_swap (xchg hi32<->lo32) then permlane16_swap (xchg odd
    // rows<->even rows) yields A-frag words j2=h and j2=h+2 for c.
    unsigned w00 = pw[0][0], w02 = pw[1][0];
    unsigned w01 = pw[0][1], w03 = pw[1][1];
    unsigned w10 = pw[2][0], w12 = pw[3][0];
    unsigned w11 = pw[2][1], w13 = pw[3][1];
    asm("v_permlane32_swap_b32 %0, %1" : "+v"(w00), "+v"(w02));
    asm("v_permlane16_swap_b32 %0, %1" : "+v"(w00), "+v"(w02));
    asm("v_permlane32_swap_b32 %0, %1" : "+v"(w01), "+v"(w03));
    asm("v_permlane16_swap_b32 %0, %1" : "+v"(w01), "+v"(w03));
    asm("v_permlane32_swap_b32 %0, %1" : "+v"(w10), "+v"(w12));
    asm("v_permlane16_swap_b32 %0, %1" : "+v"(w10), "+v"(w12));
    asm("v_permlane32_swap_b32 %0, %1" : "+v"(w11), "+v"(w13));
    asm("v_permlane16_swap_b32 %0, %1" : "+v"(w11), "+v"(w13));
    uint4v u0 = {w00, w01, w02, w03};  // W[q=l15][k=quad*8+j], k 0..31
    uint4v u1 = {w10, w11, w12, w13};  // k 32..63
    half8 af0 = __builtin_bit_cast(half8, u0);
    half8 af1 = __builtin_bit_cast(half8, u1);

#pragma unroll
    for (int nd = 0; nd < 4; ++nd) {
      const _Float16* vp =
          Vbh + (size_t)(nd * 16 + l15) * S_LEN + kt * 64 + quad * 8;
      half8 b0 = *(const half8*)vp;         // k = quad*8..+7
      half8 b1 = *(const half8*)(vp + 32);  // k = 32+quad*8..+7
      oacc[nd] = __builtin_amdgcn_mfma_f32_16x16x32_f16(af0, b0, oacc[nd], 0, 0, 0);
      oacc[nd] = __builtin_amdgcn_mfma_f32_16x16x32_f16(af1, b1, oacc[nd], 0, 0, 0);
    }
  }

  // PV D-layout: col = l15 = d-col, row = quad*4 + r = q-row
  float* __restrict__ obase =
      out + ((size_t)bh * S_LEN + q0 + wv * 16 + quad * 4) * D_DIM + l15;
#pragma unroll
  for (int nd = 0; nd < 4; ++nd)
#pragma unroll
    for (int r = 0; r < 4; ++r)
      __builtin_nontemporal_store(oacc[nd][r],
                                  obase + (size_t)r * D_DIM + nd * 16);
}

extern "C" void kernel_launch(void* const* d_in, const int* in_sizes, int n_in,
                              void* d_out, int out_size, void* d_ws, size_t ws_size,
                              hipStream_t stream) {
  (void)in_sizes; (void)n_in; (void)out_size; (void)ws_size;
  const float* q = (const float*)d_in[0];
  const float* k = (const float*)d_in[1];
  const float* v = (const float*)d_in[2];
  const int* mask = (const int*)d_in[3];

  float* out  = (float*)d_out;          // (B,H,S,D) = 4,194,304 floats
  float* wout = out + NELEM;            // (B,H,S,S) = 134,217,728 floats

  _Float16* Qh = (_Float16*)d_ws;       // 8 MiB
  _Float16* Kh = Qh + NELEM;            // 8 MiB
  _Float16* Vt = Kh + NELEM;            // 8 MiB (transposed V)

  cvt_kernel<<<dim3(1024), dim3(256), 0, stream>>>(q, k, v, Qh, Kh, Vt);
  attn_kernel<<<dim3(1024), dim3(256), 0, stream>>>(Qh, Kh, Vt, mask, out, wout);
}

// Round 2
// 659.334 us; speedup vs baseline: 1.3102x; 1.3102x over previous
//
#include <hip/hip_runtime.h>

#define S_LEN 2048
#define D_DIM 64

typedef __attribute__((ext_vector_type(8))) _Float16 half8;
typedef __attribute__((ext_vector_type(4))) _Float16 half4;
typedef __attribute__((ext_vector_type(2))) _Float16 half2v;
typedef __attribute__((ext_vector_type(4))) float    floatx4;
typedef __attribute__((ext_vector_type(4))) unsigned uint4v;

static constexpr size_t NELEM = (size_t)2 * 16 * 2048 * 64;  // 4,194,304 per tensor
// fold 1/sqrt(d)=0.125 and log2(e) into Q so softmax uses native exp2
static constexpr float QSCALE = 0.125f * 1.44269504088896340736f;

__device__ __forceinline__ void gld16(const void* g, void* l) {
  __builtin_amdgcn_global_load_lds(
      (const __attribute__((address_space(1))) unsigned*)g,
      (__attribute__((address_space(3))) unsigned*)l, 16, 0, 0);
}

// ---------------------------------------------------------------------------
// Kernel 1: fp32 -> fp16. Qh = q * (0.125*log2e), Kh = k, Vt = V^T per (b,h):
// [bh][d=64][s=2048] so PV B-frags are contiguous. 1024 blocks x 256 thr.
// ---------------------------------------------------------------------------
__global__ __launch_bounds__(256) void cvt_kernel(const float* __restrict__ q,
                                                  const float* __restrict__ k,
                                                  const float* __restrict__ v,
                                                  _Float16* __restrict__ Qh,
                                                  _Float16* __restrict__ Kh,
                                                  _Float16* __restrict__ Vt) {
  __shared__ float lds[64][65];  // +1 pad: conflict-free column reads
  const int t  = threadIdx.x;
  const int bh = blockIdx.x >> 5;
  const int st = blockIdx.x & 31;
  const size_t base = (size_t)bh * (S_LEN * D_DIM) + (size_t)st * (64 * D_DIM);

#pragma unroll
  for (int i = 0; i < 4; ++i) {
    size_t e = base + (size_t)(t + 256 * i) * 4;
    floatx4 qv = *(const floatx4*)(q + e);
    floatx4 kv = *(const floatx4*)(k + e);
    half4 qh, kh;
#pragma unroll
    for (int j = 0; j < 4; ++j) {
      qh[j] = (_Float16)(qv[j] * QSCALE);
      kh[j] = (_Float16)kv[j];
    }
    *(half4*)(Qh + e) = qh;
    *(half4*)(Kh + e) = kh;
  }

  {
    const int row = t >> 2;
    const int c4  = t & 3;
#pragma unroll
    for (int i = 0; i < 4; ++i) {
      int col = (c4 + 4 * i) * 4;
      floatx4 vv = *(const floatx4*)(v + base + (size_t)row * D_DIM + col);
      lds[row][col + 0] = vv[0];
      lds[row][col + 1] = vv[1];
      lds[row][col + 2] = vv[2];
      lds[row][col + 3] = vv[3];
    }
  }
  __syncthreads();
  {
    const int d = t >> 2;
    const int j = t & 3;
    half8 t0, t1;
#pragma unroll
    for (int u = 0; u < 8; ++u) t0[u] = (_Float16)lds[j * 16 + u][d];
#pragma unroll
    for (int u = 0; u < 8; ++u) t1[u] = (_Float16)lds[j * 16 + 8 + u][d];
    size_t ob = (size_t)bh * (D_DIM * S_LEN) + (size_t)d * S_LEN + st * 64 + j * 16;
    *(half8*)(Vt + ob)     = t0;
    *(half8*)(Vt + ob + 8) = t1;
  }
}

// ---------------------------------------------------------------------------
// Kernel 2: fused attention. One WG = (b,h) x 64 q-rows, 4 waves x 16 rows.
// K/V tiles (64x64 half = 8KB each) are staged via async global_load_lds,
// double-buffered, 2-phase pipeline: issue stage(kt+1), compute kt from LDS,
// one barrier per kt (T3 minimum recipe). Staging costs 0 VGPR and is
// amortized 4x (all waves read identical frags).
// Bank-conflict fix (rule #21, both-sides involution): global source chunk
// is pre-swizzled (c ^= row&7) so the lane-linear LDS write lands swizzled;
// ds_read applies the same XOR -> conflict-free b128 reads.
// Swapped QK^T: s = mfma(K, Q) -> softmax row lane-local; in-register C->A
// transpose via v_permlane32/16_swap (no LDS round-trip for W).
// MFMA 16x16x32 f16: A/B: idx=lane&15, k=quad*8+j; C/D: col=lane&15,
// row=quad*4+reg (learn_hip-verified).
// ---------------------------------------------------------------------------
__global__ __launch_bounds__(256, 4) void attn_kernel(
    const _Float16* __restrict__ Qh, const _Float16* __restrict__ Kh,
    const _Float16* __restrict__ Vt, const int* __restrict__ mask,
    float* __restrict__ out, float* __restrict__ wout) {
  __shared__ __align__(16) _Float16 ldsK[2][64 * 64];  // 16 KB
  __shared__ __align__(16) _Float16 ldsV[2][64 * 64];  // 16 KB
  __shared__ __align__(16) _Float16 maskh[S_LEN];      // 4 KB

  const int t    = threadIdx.x;
  // XCD-contiguous swizzle: grid 1024 % 8 == 0, each XCD gets 4 full bh.
  const int swz  = ((blockIdx.x & 7) << 7) | (blockIdx.x >> 3);
  const int bh   = swz >> 5;
  const int qt   = swz & 31;
  const int b    = bh >> 4;  // H = 16
  const int q0   = qt * 64;
  const int wv   = t >> 6;
  const int lane = t & 63;
  const int l15  = lane & 15;
  const int quad = lane >> 4;

  const int* __restrict__ mrow = mask + (size_t)b * S_LEN;
  const _Float16* __restrict__ Kbh = Kh + (size_t)bh * (S_LEN * D_DIM);
  const _Float16* __restrict__ Vbh = Vt + (size_t)bh * (D_DIM * S_LEN);

  // mask -> fp16 multiplier table in LDS (kills 8 intx4 global loads per kt)
#pragma unroll
  for (int i = 0; i < 8; ++i) {
    int idx = t + 256 * i;
    maskh[idx] = mrow[idx] ? (_Float16)1.0f : (_Float16)0.0f;
  }

  // Staging geometry: wave wv stages rows [wv*16, wv*16+16), 2 instrs of
  // 8 rows each. Lane l: row = base + (l>>3), chunk c' = l&7; the content
  // must be global chunk c' ^ (row&7)  (inverse-swizzled source).
  const int srow = wv * 16 + (lane >> 3);
  const int sc   = ((lane & 7) ^ (srow & 7)) * 8;  // halfs
  const size_t gK0 = (size_t)srow * D_DIM + sc;    // + kt*4096 per tile
  const size_t gK1 = gK0 + 8 * D_DIM;
  const size_t gV0 = (size_t)srow * S_LEN + sc;    // + kt*64 per tile
  const size_t gV1 = gV0 + 8 * S_LEN;
  _Float16* ldk0 = &ldsK[0][(wv * 16) * 64];
  _Float16* ldk8 = &ldsK[0][(wv * 16 + 8) * 64];
  _Float16* ldv0 = &ldsV[0][(wv * 16) * 64];
  _Float16* ldv8 = &ldsV[0][(wv * 16 + 8) * 64];

#define STAGE_K(kt, buf)                                                   \
  do {                                                                     \
    const _Float16* g = Kbh + (size_t)(kt) * (64 * D_DIM);                 \
    gld16(g + gK0, ldk0 + (buf) * 4096);                                   \
    gld16(g + gK1, ldk8 + (buf) * 4096);                                   \
  } while (0)
#define STAGE_V(kt, buf)                                                   \
  do {                                                                     \
    const _Float16* g = Vbh + (size_t)(kt) * 64;                           \
    gld16(g + gV0, ldv0 + (buf) * 4096);                                   \
    gld16(g + gV1, ldv8 + (buf) * 4096);                                   \
  } while (0)

  // Q fragments (B-operand): n = lane&15 = q-row, k-dim = quad*8+j
  const _Float16* Qp =
      Qh + ((size_t)bh * S_LEN + q0 + wv * 16 + l15) * D_DIM + quad * 8;
  const half8 qf0 = *(const half8*)(Qp);
  const half8 qf1 = *(const half8*)(Qp + 32);

  // ---- phase 1: row sums of exp2(scores) ----
  STAGE_K(0, 0);
  __syncthreads();  // maskh ready + K(0) staged (syncthreads drains vmcnt)

  float esum = 0.f;
  for (int kt = 0; kt < 32; ++kt) {
    const int cur = kt & 1;
    if (kt < 31) STAGE_K(kt + 1, cur ^ 1);
    const _Float16* Kt = &ldsK[cur][0];
#pragma unroll
    for (int n = 0; n < 4; ++n) {
      const int R = n * 16 + l15;
      const _Float16* kr = Kt + R * 64;
      half8 a0 = *(const half8*)(kr + ((quad ^ (R & 7)) * 8));
      half8 a1 = *(const half8*)(kr + (((4 | quad) ^ (R & 7)) * 8));
      floatx4 s = {0.f, 0.f, 0.f, 0.f};
      s = __builtin_amdgcn_mfma_f32_16x16x32_f16(a0, qf0, s, 0, 0, 0);
      s = __builtin_amdgcn_mfma_f32_16x16x32_f16(a1, qf1, s, 0, 0, 0);
      half4 mh = *(const half4*)&maskh[kt * 64 + n * 16 + quad * 4];
#pragma unroll
      for (int r = 0; r < 4; ++r)
        esum += (float)mh[r] * __builtin_exp2f(s[r]);
    }
    __syncthreads();
  }
  esum += __shfl_xor(esum, 16);
  esum += __shfl_xor(esum, 32);
  const float linv = 1.0f / esum;  // every lane: full row sum for q = l15

  // ---- phase 2: weights out + O accumulate ----
  floatx4 oacc[4];
#pragma unroll
  for (int nd = 0; nd < 4; ++nd) oacc[nd] = (floatx4){0.f, 0.f, 0.f, 0.f};

  float* __restrict__ wrow =
      wout + ((size_t)bh * S_LEN + q0 + wv * 16 + l15) * S_LEN;

  STAGE_K(0, 0);
  STAGE_V(0, 0);
  __syncthreads();

  for (int kt = 0; kt < 32; ++kt) {
    const int cur = kt & 1;
    if (kt < 31) {
      STAGE_K(kt + 1, cur ^ 1);
      STAGE_V(kt + 1, cur ^ 1);
    }
    const _Float16* Kt  = &ldsK[cur][0];
    const _Float16* Vtl = &ldsV[cur][0];

    unsigned pw[4][2];  // pw[n][h]: fp16 pair for k = 16n + 4*quad + 2h,+1
#pragma unroll
    for (int n = 0; n < 4; ++n) {
      const int R = n * 16 + l15;
      const _Float16* kr = Kt + R * 64;
      half8 a0 = *(const half8*)(kr + ((quad ^ (R & 7)) * 8));
      half8 a1 = *(const half8*)(kr + (((4 | quad) ^ (R & 7)) * 8));
      floatx4 s = {0.f, 0.f, 0.f, 0.f};
      s = __builtin_amdgcn_mfma_f32_16x16x32_f16(a0, qf0, s, 0, 0, 0);
      s = __builtin_amdgcn_mfma_f32_16x16x32_f16(a1, qf1, s, 0, 0, 0);
      half4 mh = *(const half4*)&maskh[kt * 64 + n * 16 + quad * 4];
      floatx4 w;
#pragma unroll
      for (int r = 0; r < 4; ++r)
        w[r] = (float)mh[r] * __builtin_exp2f(s[r]) * linv;
      // lane holds 4 consecutive k -> coalesced float4, pure streaming
      __builtin_nontemporal_store(
          w, (floatx4*)(wrow + kt * 64 + n * 16 + quad * 4));
      half2v h0 = {(_Float16)w[0], (_Float16)w[1]};
      half2v h1 = {(_Float16)w[2], (_Float16)w[3]};
      pw[n][0] = __builtin_bit_cast(unsigned, h0);
      pw[n][1] = __builtin_bit_cast(unsigned, h1);
    }

    // In-register C->A transpose: permlane32_swap + permlane16_swap pairs.
    unsigned w00 = pw[0][0], w02 = pw[1][0];
    unsigned w01 = pw[0][1], w03 = pw[1][1];
    unsigned w10 = pw[2][0], w12 = pw[3][0];
    unsigned w11 = pw[2][1], w13 = pw[3][1];
    asm("v_permlane32_swap_b32 %0, %1" : "+v"(w00), "+v"(w02));
    asm("v_permlane16_swap_b32 %0, %1" : "+v"(w00), "+v"(w02));
    asm("v_permlane32_swap_b32 %0, %1" : "+v"(w01), "+v"(w03));
    asm("v_permlane16_swap_b32 %0, %1" : "+v"(w01), "+v"(w03));
    asm("v_permlane32_swap_b32 %0, %1" : "+v"(w10), "+v"(w12));
    asm("v_permlane16_swap_b32 %0, %1" : "+v"(w10), "+v"(w12));
    asm("v_permlane32_swap_b32 %0, %1" : "+v"(w11), "+v"(w13));
    asm("v_permlane16_swap_b32 %0, %1" : "+v"(w11), "+v"(w13));
    uint4v u0 = {w00, w01, w02, w03};  // W[q=l15][k=quad*8+j], k 0..31
    uint4v u1 = {w10, w11, w12, w13};  // k 32..63
    half8 af0 = __builtin_bit_cast(half8, u0);
    half8 af1 = __builtin_bit_cast(half8, u1);

#pragma unroll
    for (int nd = 0; nd < 4; ++nd) {
      const int R = nd * 16 + l15;
      const _Float16* vr = Vtl + R * 64;
      half8 b0 = *(const half8*)(vr + ((quad ^ (R & 7)) * 8));
      half8 b1 = *(const half8*)(vr + (((4 | quad) ^ (R & 7)) * 8));
      oacc[nd] = __builtin_amdgcn_mfma_f32_16x16x32_f16(af0, b0, oacc[nd], 0, 0, 0);
      oacc[nd] = __builtin_amdgcn_mfma_f32_16x16x32_f16(af1, b1, oacc[nd], 0, 0, 0);
    }
    __syncthreads();
  }

  // PV D-layout: col = l15 = d-col, row = quad*4 + r = q-row
  float* __restrict__ obase =
      out + ((size_t)bh * S_LEN + q0 + wv * 16 + quad * 4) * D_DIM + l15;
#pragma unroll
  for (int nd = 0; nd < 4; ++nd)
#pragma unroll
    for (int r = 0; r < 4; ++r)
      __builtin_nontemporal_store(oacc[nd][r],
                                  obase + (size_t)r * D_DIM + nd * 16);
}

extern "C" void kernel_launch(void* const* d_in, const int* in_sizes, int n_in,
                              void* d_out, int out_size, void* d_ws, size_t ws_size,
                              hipStream_t stream) {
  (void)in_sizes; (void)n_in; (void)out_size; (void)ws_size;
  const float* q = (const float*)d_in[0];
  const float* k = (const float*)d_in[1];
  const float* v = (const float*)d_in[2];
  const int* mask = (const int*)d_in[3];

  float* out  = (float*)d_out;          // (B,H,S,D) = 4,194,304 floats
  float* wout = out + NELEM;            // (B,H,S,S) = 134,217,728 floats

  _Float16* Qh = (_Float16*)d_ws;       // 8 MiB
  _Float16* Kh = Qh + NELEM;            // 8 MiB
  _Float16* Vt = Kh + NELEM;            // 8 MiB (transposed V)

  cvt_kernel<<<dim3(1024), dim3(256), 0, stream>>>(q, k, v, Qh, Kh, Vt);
  attn_kernel<<<dim3(1024), dim3(256), 0, stream>>>(Qh, Kh, Vt, mask, out, wout);
}